// Round 4
// baseline (211.084 us; speedup 1.0000x reference)
//
#include <hip/hip_runtime.h>
#include <math.h>

// ProxyNCA loss, MFMA version.
// logit_ic = 18 * xhat_i . phat_c ;  nll_i = log(sum_c exp(logit_ic)) - logit_{i,T_i}
// Prescale both operands by sqrt(18*log2(e)) = 5.0959308, convert to bf16;
// the 16x16x32 bf16 MFMA accumulator then holds log2(e)*logit directly, so
// exp(logit) == v_exp_f32(acc): hot loop = MFMA + v_exp + v_add only.
// Round 4 vs round 3:
//  - CBLK 128->64 (pb: 64->32 regs), grid 512->1024 = 4 blocks/CU = 32 waves/CU
//    (round 3 had only 2 blocks/CU -> dep-chain stalls uncovered, MfmaUtil 20%).
//  - 2 row-tiles per inner iteration, 8 independent exp-accumulator chains.
//  - hoisted zero-quad as MFMA C operand (D and C regs are distinct -> one
//    zeroed f32x4 serves all chunks; round 3 re-zeroed per chunk).

#define NROWS 4096
#define NCLS  65536
#define DIM   64
#define CBLK  64                  // classes per block (register-resident B frags)
#define NBLK  (NCLS / CBLK)       // 1024 blocks = 4/CU
#define NCH   (CBLK / 16)         // 4 MFMA chunks of 16 classes

typedef __attribute__((ext_vector_type(8))) short short8;
typedef __attribute__((ext_vector_type(4))) float f32x4;

#define PRESCALE 5.0959308f       // sqrt(18 * log2(e))

__device__ __forceinline__ short bf16rne(float f) {
    union { float f; unsigned u; } v; v.f = f;
    unsigned r = (v.u + 0x7fffu + ((v.u >> 16) & 1u)) >> 16;
    return (short)r;
}

// ---- per-row prep: Xb = bf16(PRESCALE * xhat), st[r] = exact f32 target logit
__global__ void k_prep(const float* __restrict__ X, const float* __restrict__ P,
                       const int* __restrict__ T,
                       unsigned short* __restrict__ Xb, float* __restrict__ st) {
    int row  = blockIdx.x * 4 + (threadIdx.x >> 6);
    int lane = threadIdx.x & 63;
    int tc   = T[row];
    float xv = X[row * DIM + lane];
    float pv = P[tc  * DIM + lane];
    float x2 = xv * xv, p2 = pv * pv, xp = xv * pv;
    #pragma unroll
    for (int off = 32; off > 0; off >>= 1) {
        x2 += __shfl_xor(x2, off);
        p2 += __shfl_xor(p2, off);
        xp += __shfl_xor(xp, off);
    }
    float rx = rsqrtf(fmaxf(x2, 1e-24f));
    Xb[row * DIM + lane] = (unsigned short)bf16rne(xv * (PRESCALE * rx));
    if (lane == 0)
        st[row] = 18.0f * xp * rx * rsqrtf(fmaxf(p2, 1e-24f));
}

// ---- main: block b owns classes [b*64,(b+1)*64); sweeps all 4096 rows ----
// 8 waves; wave w handles row-tile pairs (w+16k, w+16k+8), k=0..15.
// B frags (P side) normalized/converted once into 32 regs per wave.
// mfma(P_frag, X_frag): C col = lane&15 = x-row, regs = 4 classes.
__global__ __launch_bounds__(512, 8)
void k_main(const float* __restrict__ prox, const unsigned short* __restrict__ Xb,
            float* __restrict__ psum) {
    int t = threadIdx.x;
    int w = t >> 6;
    int l = t & 63;
    int cb = blockIdx.x * CBLK;

    int lm = l & 15;         // class-in-chunk (A row) / x-row (B col)
    int lk = l >> 4;         // k-group

    // ---- one-time: load 64 classes of P (f32), normalize, convert to frags
    short8 pb[NCH][2];
    #pragma unroll
    for (int ch = 0; ch < NCH; ++ch) {
        int cls = cb + ch * 16 + lm;
        const float4* pr = reinterpret_cast<const float4*>(prox + cls * DIM + lk * 8);
        float4 a0 = pr[0], a1 = pr[1];          // k = lk*8 .. +7
        const float4* pr2 = reinterpret_cast<const float4*>(prox + cls * DIM + 32 + lk * 8);
        float4 b0 = pr2[0], b1 = pr2[1];        // k = 32 + lk*8 .. +7
        float sq = a0.x*a0.x + a0.y*a0.y + a0.z*a0.z + a0.w*a0.w
                 + a1.x*a1.x + a1.y*a1.y + a1.z*a1.z + a1.w*a1.w
                 + b0.x*b0.x + b0.y*b0.y + b0.z*b0.z + b0.w*b0.w
                 + b1.x*b1.x + b1.y*b1.y + b1.z*b1.z + b1.w*b1.w;
        sq += __shfl_xor(sq, 16);
        sq += __shfl_xor(sq, 32);
        float sc = PRESCALE * rsqrtf(fmaxf(sq, 1e-24f));
        short8 f0, f1;
        f0[0]=bf16rne(a0.x*sc); f0[1]=bf16rne(a0.y*sc); f0[2]=bf16rne(a0.z*sc); f0[3]=bf16rne(a0.w*sc);
        f0[4]=bf16rne(a1.x*sc); f0[5]=bf16rne(a1.y*sc); f0[6]=bf16rne(a1.z*sc); f0[7]=bf16rne(a1.w*sc);
        f1[0]=bf16rne(b0.x*sc); f1[1]=bf16rne(b0.y*sc); f1[2]=bf16rne(b0.z*sc); f1[3]=bf16rne(b0.w*sc);
        f1[4]=bf16rne(b1.x*sc); f1[5]=bf16rne(b1.y*sc); f1[6]=bf16rne(b1.z*sc); f1[7]=bf16rne(b1.w*sc);
        pb[ch][0] = f0;
        pb[ch][1] = f1;
    }

    const f32x4 zero = {0.0f, 0.0f, 0.0f, 0.0f};

    // ---- row sweep: 2 tiles (32 rows) per iteration
    #pragma unroll 1
    for (int it = 0; it < 16; ++it) {
        int rb0 = (w + 16 * it) * 16;
        int rb1 = rb0 + 128;
        short8 xa0 = *reinterpret_cast<const short8*>(Xb + (rb0 + lm) * DIM + lk * 8);
        short8 xa1 = *reinterpret_cast<const short8*>(Xb + (rb0 + lm) * DIM + 32 + lk * 8);
        short8 xc0 = *reinterpret_cast<const short8*>(Xb + (rb1 + lm) * DIM + lk * 8);
        short8 xc1 = *reinterpret_cast<const short8*>(Xb + (rb1 + lm) * DIM + 32 + lk * 8);

        float e00 = 0.f, e01 = 0.f, e02 = 0.f, e03 = 0.f;
        float e10 = 0.f, e11 = 0.f, e12 = 0.f, e13 = 0.f;
        #pragma unroll
        for (int ch = 0; ch < NCH; ++ch) {
            f32x4 c0 = __builtin_amdgcn_mfma_f32_16x16x32_bf16(pb[ch][0], xa0, zero, 0, 0, 0);
            c0 = __builtin_amdgcn_mfma_f32_16x16x32_bf16(pb[ch][1], xa1, c0, 0, 0, 0);
            f32x4 c1 = __builtin_amdgcn_mfma_f32_16x16x32_bf16(pb[ch][0], xc0, zero, 0, 0, 0);
            c1 = __builtin_amdgcn_mfma_f32_16x16x32_bf16(pb[ch][1], xc1, c1, 0, 0, 0);
            e00 += __builtin_amdgcn_exp2f(c0[0]);
            e01 += __builtin_amdgcn_exp2f(c0[1]);
            e02 += __builtin_amdgcn_exp2f(c0[2]);
            e03 += __builtin_amdgcn_exp2f(c0[3]);
            e10 += __builtin_amdgcn_exp2f(c1[0]);
            e11 += __builtin_amdgcn_exp2f(c1[1]);
            e12 += __builtin_amdgcn_exp2f(c1[2]);
            e13 += __builtin_amdgcn_exp2f(c1[3]);
        }
        float s0 = (e00 + e01) + (e02 + e03);
        float s1 = (e10 + e11) + (e12 + e13);
        s0 += __shfl_xor(s0, 16);
        s0 += __shfl_xor(s0, 32);
        s1 += __shfl_xor(s1, 16);
        s1 += __shfl_xor(s1, 32);
        if (l < 16) {
            psum[blockIdx.x * NROWS + rb0 + l] = s0;
            psum[blockIdx.x * NROWS + rb1 + l] = s1;
        }
    }
}

// ---- per-row: nll[r] = log(sum_b psum[b][r]) - st[r] --------------------
__global__ void k_rowred(const float* __restrict__ psum, const float* __restrict__ st,
                         float* __restrict__ nll) {
    __shared__ float red[256];
    int t = threadIdx.x;
    int r = blockIdx.x * 64 + (t & 63);
    int q = t >> 6;                     // 4 partial groups of 256 blocks
    float s = 0.0f;
    for (int i = q * 256; i < q * 256 + 256; ++i)
        s += psum[i * NROWS + r];
    red[t] = s;
    __syncthreads();
    if (t < 64) {
        float tot = red[t] + red[t + 64] + red[t + 128] + red[t + 192];
        nll[blockIdx.x * 64 + t] = logf(tot) - st[blockIdx.x * 64 + t];
    }
}

// ---- mean over rows -----------------------------------------------------
__global__ void k_final(const float* __restrict__ nll, float* __restrict__ out) {
    __shared__ float red[256];
    int t = threadIdx.x;
    float acc = 0.0f;
    for (int r = t; r < NROWS; r += 256) acc += nll[r];
    red[t] = acc;
    __syncthreads();
    #pragma unroll
    for (int off = 128; off > 0; off >>= 1) {
        if (t < off) red[t] += red[t + off];
        __syncthreads();
    }
    if (t == 0) out[0] = red[0] / (float)NROWS;
}

extern "C" void kernel_launch(void* const* d_in, const int* in_sizes, int n_in,
                              void* d_out, int out_size, void* d_ws, size_t ws_size,
                              hipStream_t stream) {
    const float* X = (const float*)d_in[0];
    const float* P = (const float*)d_in[1];
    const int*   T = (const int*)  d_in[3];   // d_in[2] = indices (unused)
    float* out = (float*)d_out;

    char* ws = (char*)d_ws;
    unsigned short* Xb = (unsigned short*)ws;                 // 512 KB
    float* st   = (float*)(ws + (512 << 10));                 // 16 KB
    float* nll  = (float*)(ws + (512 << 10) + (16 << 10));    // 16 KB
    float* psum = (float*)(ws + (1 << 20));                   // 16 MB (1024 x 4096 f32)

    k_prep  <<<NROWS / 4, 256, 0, stream>>>(X, P, T, Xb, st);
    k_main  <<<NBLK, 512, 0, stream>>>(P, Xb, psum);
    k_rowred<<<NROWS / 64, 256, 0, stream>>>(psum, st, nll);
    k_final <<<1, 256, 0, stream>>>(nll, out);
}

// Round 5
// 155.271 us; speedup vs baseline: 1.3595x; 1.3595x over previous
//
#include <hip/hip_runtime.h>
#include <math.h>

// ProxyNCA loss, MFMA version.
// logit_ic = 18 * xhat_i . phat_c ;  nll_i = log(sum_c exp(logit_ic)) - logit_{i,T_i}
// Prescale both operands by sqrt(18*log2(e)) = 5.0959308, convert to bf16;
// the 16x16x32 bf16 MFMA accumulator then holds log2(e)*logit directly, so
// exp(logit) == v_exp_f32(acc): hot loop = MFMA + v_exp + v_add only.
// Round 5 vs round 4:
//  - __launch_bounds__(512,4): round 4's (512,8) forced a 64-VGPR cap; kernel
//    needs ~90-100 -> catastrophic scratch spill (FETCH 98MB, WRITE 113MB,
//    VGPR_Count=32, 150us). Cap 128 fits with headroom; no spill.
//  - explicit prefetch of next iteration's 4 Xb fragments (rotation regs) so
//    the global-load latency hides under 16 MFMA + 32 exp of compute.
//  - keeps round 4's wins: CBLK=64 (pb=32 regs), 2 row-tiles/iter, 8
//    independent exp chains, hoisted zero-quad C operand.

#define NROWS 4096
#define NCLS  65536
#define DIM   64
#define CBLK  64                  // classes per block (register-resident B frags)
#define NBLK  (NCLS / CBLK)       // 1024 blocks
#define NCH   (CBLK / 16)         // 4 MFMA chunks of 16 classes

typedef __attribute__((ext_vector_type(8))) short short8;
typedef __attribute__((ext_vector_type(4))) float f32x4;

#define PRESCALE 5.0959308f       // sqrt(18 * log2(e))

__device__ __forceinline__ short bf16rne(float f) {
    union { float f; unsigned u; } v; v.f = f;
    unsigned r = (v.u + 0x7fffu + ((v.u >> 16) & 1u)) >> 16;
    return (short)r;
}

// ---- per-row prep: Xb = bf16(PRESCALE * xhat), st[r] = exact f32 target logit
__global__ void k_prep(const float* __restrict__ X, const float* __restrict__ P,
                       const int* __restrict__ T,
                       unsigned short* __restrict__ Xb, float* __restrict__ st) {
    int row  = blockIdx.x * 4 + (threadIdx.x >> 6);
    int lane = threadIdx.x & 63;
    int tc   = T[row];
    float xv = X[row * DIM + lane];
    float pv = P[tc  * DIM + lane];
    float x2 = xv * xv, p2 = pv * pv, xp = xv * pv;
    #pragma unroll
    for (int off = 32; off > 0; off >>= 1) {
        x2 += __shfl_xor(x2, off);
        p2 += __shfl_xor(p2, off);
        xp += __shfl_xor(xp, off);
    }
    float rx = rsqrtf(fmaxf(x2, 1e-24f));
    Xb[row * DIM + lane] = (unsigned short)bf16rne(xv * (PRESCALE * rx));
    if (lane == 0)
        st[row] = 18.0f * xp * rx * rsqrtf(fmaxf(p2, 1e-24f));
}

// ---- main: block b owns classes [b*64,(b+1)*64); sweeps all 4096 rows ----
// 8 waves; wave w handles row-tile pairs (w+16k, w+16k+8), k=0..15.
// B frags (P side) normalized/converted once into 32 regs per wave.
// mfma(P_frag, X_frag): C col = lane&15 = x-row, regs = 4 classes.
__global__ __launch_bounds__(512, 4)
void k_main(const float* __restrict__ prox, const unsigned short* __restrict__ Xb,
            float* __restrict__ psum) {
    int t = threadIdx.x;
    int w = t >> 6;
    int l = t & 63;
    int cb = blockIdx.x * CBLK;

    int lm = l & 15;         // class-in-chunk (A row) / x-row (B col)
    int lk = l >> 4;         // k-group

    // ---- one-time: load 64 classes of P (f32), normalize, convert to frags
    short8 pb[NCH][2];
    #pragma unroll
    for (int ch = 0; ch < NCH; ++ch) {
        int cls = cb + ch * 16 + lm;
        const float4* pr = reinterpret_cast<const float4*>(prox + cls * DIM + lk * 8);
        float4 a0 = pr[0], a1 = pr[1];          // k = lk*8 .. +7
        const float4* pr2 = reinterpret_cast<const float4*>(prox + cls * DIM + 32 + lk * 8);
        float4 b0 = pr2[0], b1 = pr2[1];        // k = 32 + lk*8 .. +7
        float sq = a0.x*a0.x + a0.y*a0.y + a0.z*a0.z + a0.w*a0.w
                 + a1.x*a1.x + a1.y*a1.y + a1.z*a1.z + a1.w*a1.w
                 + b0.x*b0.x + b0.y*b0.y + b0.z*b0.z + b0.w*b0.w
                 + b1.x*b1.x + b1.y*b1.y + b1.z*b1.z + b1.w*b1.w;
        sq += __shfl_xor(sq, 16);
        sq += __shfl_xor(sq, 32);
        float sc = PRESCALE * rsqrtf(fmaxf(sq, 1e-24f));
        short8 f0, f1;
        f0[0]=bf16rne(a0.x*sc); f0[1]=bf16rne(a0.y*sc); f0[2]=bf16rne(a0.z*sc); f0[3]=bf16rne(a0.w*sc);
        f0[4]=bf16rne(a1.x*sc); f0[5]=bf16rne(a1.y*sc); f0[6]=bf16rne(a1.z*sc); f0[7]=bf16rne(a1.w*sc);
        f1[0]=bf16rne(b0.x*sc); f1[1]=bf16rne(b0.y*sc); f1[2]=bf16rne(b0.z*sc); f1[3]=bf16rne(b0.w*sc);
        f1[4]=bf16rne(b1.x*sc); f1[5]=bf16rne(b1.y*sc); f1[6]=bf16rne(b1.z*sc); f1[7]=bf16rne(b1.w*sc);
        pb[ch][0] = f0;
        pb[ch][1] = f1;
    }

    const f32x4 zero = {0.0f, 0.0f, 0.0f, 0.0f};

    // ---- row sweep: 2 tiles (32 rows) per iteration, next-iter Xb prefetch
    short8 xa0 = *reinterpret_cast<const short8*>(Xb + (w * 16 + lm) * DIM + lk * 8);
    short8 xa1 = *reinterpret_cast<const short8*>(Xb + (w * 16 + lm) * DIM + 32 + lk * 8);
    short8 xc0 = *reinterpret_cast<const short8*>(Xb + (w * 16 + 128 + lm) * DIM + lk * 8);
    short8 xc1 = *reinterpret_cast<const short8*>(Xb + (w * 16 + 128 + lm) * DIM + 32 + lk * 8);

    #pragma unroll 1
    for (int it = 0; it < 16; ++it) {
        int rb0 = (w + 16 * it) * 16;
        int rb1 = rb0 + 128;

        short8 ca0 = xa0, ca1 = xa1, cc0 = xc0, cc1 = xc1;
        if (it < 15) {
            int nb0 = rb0 + 256;          // next iteration's first tile rows
            xa0 = *reinterpret_cast<const short8*>(Xb + (nb0 + lm) * DIM + lk * 8);
            xa1 = *reinterpret_cast<const short8*>(Xb + (nb0 + lm) * DIM + 32 + lk * 8);
            xc0 = *reinterpret_cast<const short8*>(Xb + (nb0 + 128 + lm) * DIM + lk * 8);
            xc1 = *reinterpret_cast<const short8*>(Xb + (nb0 + 128 + lm) * DIM + 32 + lk * 8);
        }

        float e00 = 0.f, e01 = 0.f, e02 = 0.f, e03 = 0.f;
        float e10 = 0.f, e11 = 0.f, e12 = 0.f, e13 = 0.f;
        #pragma unroll
        for (int ch = 0; ch < NCH; ++ch) {
            f32x4 c0 = __builtin_amdgcn_mfma_f32_16x16x32_bf16(pb[ch][0], ca0, zero, 0, 0, 0);
            c0 = __builtin_amdgcn_mfma_f32_16x16x32_bf16(pb[ch][1], ca1, c0, 0, 0, 0);
            f32x4 c1 = __builtin_amdgcn_mfma_f32_16x16x32_bf16(pb[ch][0], cc0, zero, 0, 0, 0);
            c1 = __builtin_amdgcn_mfma_f32_16x16x32_bf16(pb[ch][1], cc1, c1, 0, 0, 0);
            e00 += __builtin_amdgcn_exp2f(c0[0]);
            e01 += __builtin_amdgcn_exp2f(c0[1]);
            e02 += __builtin_amdgcn_exp2f(c0[2]);
            e03 += __builtin_amdgcn_exp2f(c0[3]);
            e10 += __builtin_amdgcn_exp2f(c1[0]);
            e11 += __builtin_amdgcn_exp2f(c1[1]);
            e12 += __builtin_amdgcn_exp2f(c1[2]);
            e13 += __builtin_amdgcn_exp2f(c1[3]);
        }
        float s0 = (e00 + e01) + (e02 + e03);
        float s1 = (e10 + e11) + (e12 + e13);
        s0 += __shfl_xor(s0, 16);
        s0 += __shfl_xor(s0, 32);
        s1 += __shfl_xor(s1, 16);
        s1 += __shfl_xor(s1, 32);
        if (l < 16) {
            psum[blockIdx.x * NROWS + rb0 + l] = s0;
            psum[blockIdx.x * NROWS + rb1 + l] = s1;
        }
    }
}

// ---- per-row: nll[r] = log(sum_b psum[b][r]) - st[r] --------------------
__global__ void k_rowred(const float* __restrict__ psum, const float* __restrict__ st,
                         float* __restrict__ nll) {
    __shared__ float red[256];
    int t = threadIdx.x;
    int r = blockIdx.x * 64 + (t & 63);
    int q = t >> 6;                     // 4 partial groups of 256 blocks
    float s = 0.0f;
    for (int i = q * 256; i < q * 256 + 256; ++i)
        s += psum[i * NROWS + r];
    red[t] = s;
    __syncthreads();
    if (t < 64) {
        float tot = red[t] + red[t + 64] + red[t + 128] + red[t + 192];
        nll[blockIdx.x * 64 + t] = logf(tot) - st[blockIdx.x * 64 + t];
    }
}

// ---- mean over rows -----------------------------------------------------
__global__ void k_final(const float* __restrict__ nll, float* __restrict__ out) {
    __shared__ float red[256];
    int t = threadIdx.x;
    float acc = 0.0f;
    for (int r = t; r < NROWS; r += 256) acc += nll[r];
    red[t] = acc;
    __syncthreads();
    #pragma unroll
    for (int off = 128; off > 0; off >>= 1) {
        if (t < off) red[t] += red[t + off];
        __syncthreads();
    }
    if (t == 0) out[0] = red[0] / (float)NROWS;
}

extern "C" void kernel_launch(void* const* d_in, const int* in_sizes, int n_in,
                              void* d_out, int out_size, void* d_ws, size_t ws_size,
                              hipStream_t stream) {
    const float* X = (const float*)d_in[0];
    const float* P = (const float*)d_in[1];
    const int*   T = (const int*)  d_in[3];   // d_in[2] = indices (unused)
    float* out = (float*)d_out;

    char* ws = (char*)d_ws;
    unsigned short* Xb = (unsigned short*)ws;                 // 512 KB
    float* st   = (float*)(ws + (512 << 10));                 // 16 KB
    float* nll  = (float*)(ws + (512 << 10) + (16 << 10));    // 16 KB
    float* psum = (float*)(ws + (1 << 20));                   // 16 MB (1024 x 4096 f32)

    k_prep  <<<NROWS / 4, 256, 0, stream>>>(X, P, T, Xb, st);
    k_main  <<<NBLK, 512, 0, stream>>>(P, Xb, psum);
    k_rowred<<<NROWS / 64, 256, 0, stream>>>(psum, st, nll);
    k_final <<<1, 256, 0, stream>>>(nll, out);
}

// Round 6
// 139.655 us; speedup vs baseline: 1.5115x; 1.1118x over previous
//
#include <hip/hip_runtime.h>
#include <math.h>

// ProxyNCA loss, MFMA class-sweep version.
// logit_ic = 18 * xhat_i . phat_c ;  nll_i = log(sum_c exp(logit_ic)) - logit_{i,T_i}
// Both operands prescaled by sqrt(18*log2(e)) = 5.0959308 in bf16; the
// 16x16x32 bf16 MFMA accumulator holds log2(e)*logit, so exp = v_exp_f32.
// Round 6 vs round 5: rounds 3-5 plateaued at 69-88us with MfmaUtil<20% and
// VALUBusy<45% -- in-order per-wave stalls from the per-iteration
// shfl/add/store tail + Xb re-streaming. Restructure to class-sweep:
//  - wave owns 32 rows (X frags fixed in 16 VGPRs), sweeps 2048 classes.
//  - proxies pre-normalized to bf16 ONCE (k_prep_p) and streamed as MFMA
//    A-frags with 2-body register prefetch. No LDS, no barriers in loop.
//  - exp-sums live in 8 register chains across the whole sweep; shuffle +
//    psum store ONCE per wave (was per 32-row iteration).
//  - psum shrinks 16MB -> 512KB.

#define NROWS 4096
#define NCLS  65536
#define DIM   64
#define NSPLIT 32                 // class splits
#define CSPL  (NCLS / NSPLIT)     // 2048 classes per block
#define NRB   16                  // row blocks
#define RPB   (NROWS / NRB)       // 256 rows per block (8 waves x 32)
#define NIT   (CSPL / 16)         // 128 chunk iterations

typedef __attribute__((ext_vector_type(8))) short short8;
typedef __attribute__((ext_vector_type(4))) float f32x4;

#define PRESCALE 5.0959308f       // sqrt(18 * log2(e))

__device__ __forceinline__ short bf16rne(float f) {
    union { float f; unsigned u; } v; v.f = f;
    unsigned r = (v.u + 0x7fffu + ((v.u >> 16) & 1u)) >> 16;
    return (short)r;
}

// ---- proxies -> prescaled-normalized bf16 (once per class) --------------
__global__ void k_prep_p(const float* __restrict__ P, unsigned short* __restrict__ Pb) {
    int row  = blockIdx.x * 4 + (threadIdx.x >> 6);
    int lane = threadIdx.x & 63;
    float v  = P[row * DIM + lane];
    float sq = v * v;
    #pragma unroll
    for (int off = 32; off > 0; off >>= 1) sq += __shfl_xor(sq, off);
    float sc = PRESCALE * rsqrtf(fmaxf(sq, 1e-24f));
    Pb[row * DIM + lane] = (unsigned short)bf16rne(v * sc);
}

// ---- X -> bf16 frags + exact-f32 target logit ---------------------------
__global__ void k_prep(const float* __restrict__ X, const float* __restrict__ P,
                       const int* __restrict__ T,
                       unsigned short* __restrict__ Xb, float* __restrict__ st) {
    int row  = blockIdx.x * 4 + (threadIdx.x >> 6);
    int lane = threadIdx.x & 63;
    int tc   = T[row];
    float xv = X[row * DIM + lane];
    float pv = P[tc  * DIM + lane];
    float x2 = xv * xv, p2 = pv * pv, xp = xv * pv;
    #pragma unroll
    for (int off = 32; off > 0; off >>= 1) {
        x2 += __shfl_xor(x2, off);
        p2 += __shfl_xor(p2, off);
        xp += __shfl_xor(xp, off);
    }
    float rx = rsqrtf(fmaxf(x2, 1e-24f));
    Xb[row * DIM + lane] = (unsigned short)bf16rne(xv * (PRESCALE * rx));
    if (lane == 0)
        st[row] = 18.0f * xp * rx * rsqrtf(fmaxf(p2, 1e-24f));
}

// ---- main: block (rb, sp) = rows [rb*256,+256) x classes [sp*2048,+2048) ----
// wave w owns rows rowbase = rb*256 + w*32 .. +31 (2 MFMA row-tiles, fixed X).
// Sweeps 128 chunks of 16 classes; P frags streamed with 2-body prefetch.
// mfma(P_frag, X_frag): C col = lane&15 = x-row; class = chunk*16 + lk*4 + reg.
__global__ __launch_bounds__(512, 4)
void k_main(const unsigned short* __restrict__ Pb, const unsigned short* __restrict__ Xb,
            float* __restrict__ psum) {
    int t  = threadIdx.x;
    int w  = t >> 6;
    int l  = t & 63;
    int bx = blockIdx.x;
    int rb = bx & (NRB - 1);
    int sp = bx >> 4;
    int lm = l & 15;
    int lk = l >> 4;

    int rowbase = rb * RPB + w * 32;
    short8 x00 = *reinterpret_cast<const short8*>(Xb + (rowbase +      lm) * DIM +      lk * 8);
    short8 x01 = *reinterpret_cast<const short8*>(Xb + (rowbase +      lm) * DIM + 32 + lk * 8);
    short8 x10 = *reinterpret_cast<const short8*>(Xb + (rowbase + 16 + lm) * DIM +      lk * 8);
    short8 x11 = *reinterpret_cast<const short8*>(Xb + (rowbase + 16 + lm) * DIM + 32 + lk * 8);

    const unsigned short* Pbase = Pb + (size_t)sp * CSPL * DIM;

    const f32x4 zero = {0.0f, 0.0f, 0.0f, 0.0f};
    float e00 = 0.f, e01 = 0.f, e02 = 0.f, e03 = 0.f;
    float e10 = 0.f, e11 = 0.f, e12 = 0.f, e13 = 0.f;

    // prologue: chunks 0 and 1
    short8 pa0 = *reinterpret_cast<const short8*>(Pbase + (0 * 16 + lm) * DIM +      lk * 8);
    short8 pa1 = *reinterpret_cast<const short8*>(Pbase + (0 * 16 + lm) * DIM + 32 + lk * 8);
    short8 qb0 = *reinterpret_cast<const short8*>(Pbase + (1 * 16 + lm) * DIM +      lk * 8);
    short8 qb1 = *reinterpret_cast<const short8*>(Pbase + (1 * 16 + lm) * DIM + 32 + lk * 8);

    #pragma unroll 1
    for (int it = 0; it < NIT; it += 2) {
        int nx = (it + 2 < NIT) ? (it + 2) : 0;   // clamp: last loads redundant, not UB
        short8 na0 = *reinterpret_cast<const short8*>(Pbase + ((nx    ) * 16 + lm) * DIM +      lk * 8);
        short8 na1 = *reinterpret_cast<const short8*>(Pbase + ((nx    ) * 16 + lm) * DIM + 32 + lk * 8);
        short8 nb0 = *reinterpret_cast<const short8*>(Pbase + ((nx + 1) * 16 + lm) * DIM +      lk * 8);
        short8 nb1 = *reinterpret_cast<const short8*>(Pbase + ((nx + 1) * 16 + lm) * DIM + 32 + lk * 8);

        // chunk it
        f32x4 c0 = __builtin_amdgcn_mfma_f32_16x16x32_bf16(pa0, x00, zero, 0, 0, 0);
        c0 = __builtin_amdgcn_mfma_f32_16x16x32_bf16(pa1, x01, c0, 0, 0, 0);
        f32x4 c1 = __builtin_amdgcn_mfma_f32_16x16x32_bf16(pa0, x10, zero, 0, 0, 0);
        c1 = __builtin_amdgcn_mfma_f32_16x16x32_bf16(pa1, x11, c1, 0, 0, 0);
        e00 += __builtin_amdgcn_exp2f(c0[0]);
        e01 += __builtin_amdgcn_exp2f(c0[1]);
        e02 += __builtin_amdgcn_exp2f(c0[2]);
        e03 += __builtin_amdgcn_exp2f(c0[3]);
        e10 += __builtin_amdgcn_exp2f(c1[0]);
        e11 += __builtin_amdgcn_exp2f(c1[1]);
        e12 += __builtin_amdgcn_exp2f(c1[2]);
        e13 += __builtin_amdgcn_exp2f(c1[3]);

        // chunk it+1
        f32x4 d0 = __builtin_amdgcn_mfma_f32_16x16x32_bf16(qb0, x00, zero, 0, 0, 0);
        d0 = __builtin_amdgcn_mfma_f32_16x16x32_bf16(qb1, x01, d0, 0, 0, 0);
        f32x4 d1 = __builtin_amdgcn_mfma_f32_16x16x32_bf16(qb0, x10, zero, 0, 0, 0);
        d1 = __builtin_amdgcn_mfma_f32_16x16x32_bf16(qb1, x11, d1, 0, 0, 0);
        e00 += __builtin_amdgcn_exp2f(d0[0]);
        e01 += __builtin_amdgcn_exp2f(d0[1]);
        e02 += __builtin_amdgcn_exp2f(d0[2]);
        e03 += __builtin_amdgcn_exp2f(d0[3]);
        e10 += __builtin_amdgcn_exp2f(d1[0]);
        e11 += __builtin_amdgcn_exp2f(d1[1]);
        e12 += __builtin_amdgcn_exp2f(d1[2]);
        e13 += __builtin_amdgcn_exp2f(d1[3]);

        pa0 = na0; pa1 = na1; qb0 = nb0; qb1 = nb1;
    }

    // once-per-wave reduction: sum the 4 lk-groups for each row
    float s0 = (e00 + e01) + (e02 + e03);
    float s1 = (e10 + e11) + (e12 + e13);
    s0 += __shfl_xor(s0, 16);
    s0 += __shfl_xor(s0, 32);
    s1 += __shfl_xor(s1, 16);
    s1 += __shfl_xor(s1, 32);
    if (l < 16) {
        psum[sp * NROWS + rowbase + l]      = s0;
        psum[sp * NROWS + rowbase + 16 + l] = s1;
    }
}

// ---- per-row: nll[r] = log(sum_sp psum[sp][r]) - st[r] ------------------
__global__ void k_rowred(const float* __restrict__ psum, const float* __restrict__ st,
                         float* __restrict__ nll) {
    int r = blockIdx.x * 256 + threadIdx.x;
    float s = 0.0f;
    #pragma unroll
    for (int i = 0; i < NSPLIT; ++i)
        s += psum[i * NROWS + r];
    nll[r] = logf(s) - st[r];
}

// ---- mean over rows -----------------------------------------------------
__global__ void k_final(const float* __restrict__ nll, float* __restrict__ out) {
    __shared__ float red[256];
    int t = threadIdx.x;
    float acc = 0.0f;
    for (int r = t; r < NROWS; r += 256) acc += nll[r];
    red[t] = acc;
    __syncthreads();
    #pragma unroll
    for (int off = 128; off > 0; off >>= 1) {
        if (t < off) red[t] += red[t + off];
        __syncthreads();
    }
    if (t == 0) out[0] = red[0] / (float)NROWS;
}

extern "C" void kernel_launch(void* const* d_in, const int* in_sizes, int n_in,
                              void* d_out, int out_size, void* d_ws, size_t ws_size,
                              hipStream_t stream) {
    const float* X = (const float*)d_in[0];
    const float* P = (const float*)d_in[1];
    const int*   T = (const int*)  d_in[3];   // d_in[2] = indices (unused)
    float* out = (float*)d_out;

    char* ws = (char*)d_ws;
    unsigned short* Xb = (unsigned short*)ws;                 // 512 KB
    float* st   = (float*)(ws + (512 << 10));                 // 16 KB
    float* nll  = (float*)(ws + (528 << 10));                 // 16 KB
    unsigned short* Pb = (unsigned short*)(ws + (1 << 20));   // 8 MB
    float* psum = (float*)(ws + (9 << 20));                   // 512 KB (32 x 4096)

    k_prep_p<<<NCLS / 4, 256, 0, stream>>>(P, Pb);
    k_prep  <<<NROWS / 4, 256, 0, stream>>>(X, P, T, Xb, st);
    k_main  <<<NRB * NSPLIT, 512, 0, stream>>>(Pb, Xb, psum);
    k_rowred<<<NROWS / 256, 256, 0, stream>>>(psum, st, nll);
    k_final <<<1, 256, 0, stream>>>(nll, out);
}